// Round 1
// baseline (896.995 us; speedup 1.0000x reference)
//
#include <hip/hip_runtime.h>
#include <hip/hip_bf16.h>

// Problem constants (fixed shapes from setup_inputs)
#define M_DIM 8192   // B*S = 4*2048
#define N_DIM 4096   // D_OUT
#define DK    4096   // D_IN
#define R_DIM 64
#define KX    4160   // DK + R_DIM (K-extended GEMM)
// SCALE = ALPHA/K = 16/16 = 1.0

typedef __bf16 bf16x8 __attribute__((ext_vector_type(8)));
typedef float f32x4 __attribute__((ext_vector_type(4)));
typedef unsigned short ushort8 __attribute__((ext_vector_type(8)));

__device__ __forceinline__ unsigned short f2bf_rne(float f) {
  union { float f; unsigned int u; } v; v.f = f;
  unsigned int u = v.u;
  return (unsigned short)((u + 0x7fffu + ((u >> 16) & 1u)) >> 16);
}

// async global->LDS, 16B per lane; lds dest is wave-uniform base + lane*16
__device__ __forceinline__ void load16_to_lds(const void* g, void* l) {
  __builtin_amdgcn_global_load_lds(
      (__attribute__((address_space(1))) void*)(unsigned long long)(const char*)g,
      (__attribute__((address_space(3))) void*)(unsigned int)(unsigned long long)(char*)l,
      16, 0, 0);
}

// ---------------- fp32 -> bf16 conversion into K-extended layout ----------------
__global__ __launch_bounds__(256) void cvt_bf16_kernel(
    const float* __restrict__ src, unsigned short* __restrict__ dst,
    int shift, int mask, int rowstride, int coloff, long long total) {
  long long idx = ((long long)blockIdx.x * 256 + threadIdx.x) * 8;
  if (idx >= total) return;
  long long row = idx >> shift;
  int col = (int)(idx & mask);
  float4 f0 = *(const float4*)(src + idx);
  float4 f1 = *(const float4*)(src + idx + 4);
  ushort8 o;
  o[0] = f2bf_rne(f0.x); o[1] = f2bf_rne(f0.y);
  o[2] = f2bf_rne(f0.z); o[3] = f2bf_rne(f0.w);
  o[4] = f2bf_rne(f1.x); o[5] = f2bf_rne(f1.y);
  o[6] = f2bf_rne(f1.z); o[7] = f2bf_rne(f1.w);
  *(ushort8*)(dst + row * (long long)rowstride + coloff + col) = o;
}

// ---------------- z = x@A^T, soft top-k mask, write bf16 into x_ext tail ----------------
__global__ __launch_bounds__(256) void zmask_kernel(
    const float* __restrict__ x, const float* __restrict__ A,
    unsigned short* __restrict__ xext) {
  __shared__ float xs[DK];
  __shared__ float zrow[R_DIM];
  const int m = blockIdx.x;
  const int tid = threadIdx.x;

  // stage x[m,:] into LDS (16 KB) with float4 loads
  const float4* xrow = (const float4*)(x + (size_t)m * DK);
  float4* xs4 = (float4*)xs;
  for (int i = tid; i < DK / 4; i += 256) xs4[i] = xrow[i];
  __syncthreads();

  // 4 threads per r-row; each does 1/4 of the dot with float4 loads
  const int r = tid >> 2, p = tid & 3;
  const float4* arow = (const float4*)(A + (size_t)r * DK);
  float acc = 0.f;
#pragma unroll 8
  for (int i = 0; i < DK / 16; ++i) {
    int d4 = p + i * 4;
    float4 a4 = arow[d4];
    float4 x4 = xs4[d4];
    acc += a4.x * x4.x + a4.y * x4.y + a4.z * x4.z + a4.w * x4.w;
  }
  acc += __shfl_xor(acc, 1);
  acc += __shfl_xor(acc, 2);
  if (p == 0) zrow[r] = acc;
  __syncthreads();

  if (tid < 64) {
    float v = zrow[tid];
    float a = fabsf(v);
    // rank-select the 16th-largest |z| (tie-safe): threshold lane satisfies
    // cnt_gt <= 15 < cnt_ge
    int cnt_gt = 0, cnt_ge = 0;
#pragma unroll
    for (int i = 0; i < 64; ++i) {
      float o = __shfl(a, i);
      cnt_gt += (o > a) ? 1 : 0;
      cnt_ge += (o >= a) ? 1 : 0;
    }
    float cand = (cnt_gt <= 15 && cnt_ge > 15) ? a : -1.f;
#pragma unroll
    for (int off = 32; off; off >>= 1) cand = fmaxf(cand, __shfl_xor(cand, off));
    float thr = cand;
    float mask = 1.f / (1.f + __expf(-(a - thr) * 10.0f));  // TEMP=0.1
    float zs = v * mask;  // SCALE == 1.0
    xext[(size_t)m * KX + DK + tid] = f2bf_rne(zs);
  }
}

// ---------------- main GEMM: out[m][n] = sum_k xext[m][k]*wext[n][k] + bias[n] ----------------
// 128x128 tile, BK=32, 4 waves in 2x2, 4x4 16x16x32 MFMA per wave (m97 structure)
__global__ __launch_bounds__(256) void gemm_kernel(
    const unsigned short* __restrict__ Ag,   // [M_DIM][KX] bf16
    const unsigned short* __restrict__ Bg,   // [N_DIM][KX] bf16
    const float* __restrict__ bias,
    float* __restrict__ out) {
  __shared__ unsigned short As[128][32];  // 8 KB
  __shared__ unsigned short Bs[128][32];  // 8 KB

  const int tid = threadIdx.x;
  const int wave = tid >> 6;
  const int lane = tid & 63;
  const int bn = blockIdx.x, bm = blockIdx.y;
  const int rowBase = bm * 128, colBase = bn * 128;
  const int wm = (wave & 1) * 64, wn = (wave >> 1) * 64;

  // staging: wave w loads 1KB chunks c0=w and c1=w+4 of each 8KB tile
  const int c0 = wave, c1 = wave + 4;
  const int srow = lane >> 2;
  const int sseg = (lane & 3) * 8;

  const unsigned short* aP0 = Ag + (size_t)(rowBase + c0 * 16 + srow) * KX + sseg;
  const unsigned short* aP1 = Ag + (size_t)(rowBase + c1 * 16 + srow) * KX + sseg;
  const unsigned short* bP0 = Bg + (size_t)(colBase + c0 * 16 + srow) * KX + sseg;
  const unsigned short* bP1 = Bg + (size_t)(colBase + c1 * 16 + srow) * KX + sseg;
  unsigned short* aL0 = &As[c0 * 16][0];
  unsigned short* aL1 = &As[c1 * 16][0];
  unsigned short* bL0 = &Bs[c0 * 16][0];
  unsigned short* bL1 = &Bs[c1 * 16][0];

  f32x4 acc[4][4] = {};
  const int fr = lane & 15;
  const int fk = (lane >> 4) * 8;

  for (int k0 = 0; k0 < KX; k0 += 32) {
    __syncthreads();
    load16_to_lds(aP0 + k0, aL0);
    load16_to_lds(aP1 + k0, aL1);
    load16_to_lds(bP0 + k0, bL0);
    load16_to_lds(bP1 + k0, bL1);
    __syncthreads();

    bf16x8 afrag[4], bfrag[4];
#pragma unroll
    for (int i = 0; i < 4; ++i)
      afrag[i] = *(const bf16x8*)&As[wm + i * 16 + fr][fk];
#pragma unroll
    for (int j = 0; j < 4; ++j)
      bfrag[j] = *(const bf16x8*)&Bs[wn + j * 16 + fr][fk];
#pragma unroll
    for (int i = 0; i < 4; ++i)
#pragma unroll
      for (int j = 0; j < 4; ++j)
        acc[i][j] = __builtin_amdgcn_mfma_f32_16x16x32_bf16(afrag[i], bfrag[j],
                                                            acc[i][j], 0, 0, 0);
  }

  // epilogue: C/D layout col=lane&15, row=(lane>>4)*4+reg
  const int quad = lane >> 4;
#pragma unroll
  for (int j = 0; j < 4; ++j) {
    int col = colBase + wn + j * 16 + fr;
    float bv = bias[col];
#pragma unroll
    for (int i = 0; i < 4; ++i) {
      int row0 = rowBase + wm + i * 16 + quad * 4;
#pragma unroll
      for (int r = 0; r < 4; ++r)
        out[(size_t)(row0 + r) * N_DIM + col] = acc[i][j][r] + bv;
    }
  }
}

extern "C" void kernel_launch(void* const* d_in, const int* in_sizes, int n_in,
                              void* d_out, int out_size, void* d_ws, size_t ws_size,
                              hipStream_t stream) {
  const float* x    = (const float*)d_in[0];  // (4,2048,4096)
  const float* A    = (const float*)d_in[1];  // (64,4096)
  const float* B    = (const float*)d_in[2];  // (4096,64)
  const float* W    = (const float*)d_in[3];  // (4096,4096)
  const float* bias = (const float*)d_in[4];  // (4096,)
  float* out = (float*)d_out;

  // workspace: x_ext [8192][4160] bf16 (68.2 MB) + w_ext [4096][4160] bf16 (34.1 MB)
  unsigned short* xext = (unsigned short*)d_ws;
  unsigned short* wext = xext + (size_t)M_DIM * KX;

  // x -> x_ext[:, :4096]
  cvt_bf16_kernel<<<(M_DIM * DK / 8 + 255) / 256, 256, 0, stream>>>(
      x, xext, 12, 4095, KX, 0, (long long)M_DIM * DK);
  // W -> w_ext[:, :4096]
  cvt_bf16_kernel<<<(N_DIM * DK / 8 + 255) / 256, 256, 0, stream>>>(
      W, wext, 12, 4095, KX, 0, (long long)N_DIM * DK);
  // B -> w_ext[:, 4096:]
  cvt_bf16_kernel<<<(N_DIM * R_DIM / 8 + 255) / 256, 256, 0, stream>>>(
      B, wext, 6, 63, KX, 4096, (long long)N_DIM * R_DIM);
  // z = x@A^T, soft-topk, -> x_ext[:, 4096:]
  zmask_kernel<<<M_DIM, 256, 0, stream>>>(x, A, xext);

  dim3 grid(N_DIM / 128, M_DIM / 128);  // 32 x 64
  gemm_kernel<<<grid, 256, 0, stream>>>(xext, wext, bias, out);
}

// Round 2
// 609.220 us; speedup vs baseline: 1.4724x; 1.4724x over previous
//
#include <hip/hip_runtime.h>
#include <hip/hip_bf16.h>

// Problem constants (fixed shapes from setup_inputs)
#define M_DIM 8192   // B*S = 4*2048
#define N_DIM 4096   // D_OUT
#define DK    4096   // D_IN
#define R_DIM 64
#define KX    4160   // DK + R_DIM (K-extended GEMM)
#define SPLITK 8
#define KCHUNK (DK / SPLITK)  // 512
// SCALE = ALPHA/K = 16/16 = 1.0

typedef __bf16 bf16x8 __attribute__((ext_vector_type(8)));
typedef float f32x4 __attribute__((ext_vector_type(4)));
typedef unsigned short ushort8 __attribute__((ext_vector_type(8)));

__device__ __forceinline__ unsigned short f2bf_rne(float f) {
  union { float f; unsigned int u; } v; v.f = f;
  unsigned int u = v.u;
  return (unsigned short)((u + 0x7fffu + ((u >> 16) & 1u)) >> 16);
}

// async global->LDS, 16B per lane; lds dest is wave-uniform base + lane*16
__device__ __forceinline__ void load16_to_lds(const void* g, void* l) {
  __builtin_amdgcn_global_load_lds(
      (__attribute__((address_space(1))) void*)(unsigned long long)(const char*)g,
      (__attribute__((address_space(3))) void*)(unsigned int)(unsigned long long)(char*)l,
      16, 0, 0);
}

// ---------------- fp32 -> bf16 conversion into strided layout ----------------
__global__ __launch_bounds__(256) void cvt_bf16_kernel(
    const float* __restrict__ src, unsigned short* __restrict__ dst,
    int shift, int mask, int rowstride, int coloff, long long total) {
  long long idx = ((long long)blockIdx.x * 256 + threadIdx.x) * 8;
  if (idx >= total) return;
  long long row = idx >> shift;
  int col = (int)(idx & mask);
  float4 f0 = *(const float4*)(src + idx);
  float4 f1 = *(const float4*)(src + idx + 4);
  ushort8 o;
  o[0] = f2bf_rne(f0.x); o[1] = f2bf_rne(f0.y);
  o[2] = f2bf_rne(f0.z); o[3] = f2bf_rne(f0.w);
  o[4] = f2bf_rne(f1.x); o[5] = f2bf_rne(f1.y);
  o[6] = f2bf_rne(f1.z); o[7] = f2bf_rne(f1.w);
  *(ushort8*)(dst + row * (long long)rowstride + coloff + col) = o;
}

// ---------------- z partials: zpart[kc] = xext[:, kc*512:(kc+1)*512] @ Abf^T ----------------
// tile 128 rows x 64 cols, 4 waves each own 32 rows x 64 cols (2x4 16x16x32 MFMA)
__global__ __launch_bounds__(256) void zgemm_kernel(
    const unsigned short* __restrict__ Xg,   // [M_DIM][KX] bf16
    const unsigned short* __restrict__ Ab,   // [R_DIM][DK] bf16
    float* __restrict__ zpart) {             // [SPLITK][M_DIM][64] fp32
  __shared__ unsigned short As[128][32];  // 8 KB (x rows)
  __shared__ unsigned short Bs[64][32];   // 4 KB (A rows)

  const int tid = threadIdx.x;
  const int wave = tid >> 6;
  const int lane = tid & 63;
  const int rowBase = blockIdx.x * 128;
  const int kc = blockIdx.y;
  const int kBase = kc * KCHUNK;
  const int wm = wave * 32;

  const int c0 = wave, c1 = wave + 4;
  const int srow = lane >> 2;
  const int sseg = (lane & 3) * 8;

  const unsigned short* aP0 = Xg + (size_t)(rowBase + c0 * 16 + srow) * KX + kBase + sseg;
  const unsigned short* aP1 = Xg + (size_t)(rowBase + c1 * 16 + srow) * KX + kBase + sseg;
  const unsigned short* bP0 = Ab + (size_t)(wave * 16 + srow) * DK + kBase + sseg;
  unsigned short* aL0 = &As[c0 * 16][0];
  unsigned short* aL1 = &As[c1 * 16][0];
  unsigned short* bL0 = &Bs[wave * 16][0];

  f32x4 acc[2][4] = {};
  const int fr = lane & 15;
  const int fk = (lane >> 4) * 8;

  for (int k0 = 0; k0 < KCHUNK; k0 += 32) {
    __syncthreads();
    load16_to_lds(aP0 + k0, aL0);
    load16_to_lds(aP1 + k0, aL1);
    load16_to_lds(bP0 + k0, bL0);
    __syncthreads();

    bf16x8 afrag[2], bfrag[4];
#pragma unroll
    for (int i = 0; i < 2; ++i)
      afrag[i] = *(const bf16x8*)&As[wm + i * 16 + fr][fk];
#pragma unroll
    for (int j = 0; j < 4; ++j)
      bfrag[j] = *(const bf16x8*)&Bs[j * 16 + fr][fk];
#pragma unroll
    for (int i = 0; i < 2; ++i)
#pragma unroll
      for (int j = 0; j < 4; ++j)
        acc[i][j] = __builtin_amdgcn_mfma_f32_16x16x32_bf16(afrag[i], bfrag[j],
                                                            acc[i][j], 0, 0, 0);
  }

  const int quad = lane >> 4;
#pragma unroll
  for (int j = 0; j < 4; ++j) {
    int col = j * 16 + fr;
#pragma unroll
    for (int i = 0; i < 2; ++i) {
      int row0 = rowBase + wm + i * 16 + quad * 4;
#pragma unroll
      for (int r = 0; r < 4; ++r)
        zpart[((size_t)kc * M_DIM + row0 + r) * R_DIM + col] = acc[i][j][r];
    }
  }
}

// ---------------- reduce partials, soft top-k mask, write bf16 into x_ext tail ----------------
// one wave per row
__global__ __launch_bounds__(256) void mask_kernel(
    const float* __restrict__ zpart, unsigned short* __restrict__ xext) {
  const int wave = threadIdx.x >> 6;
  const int lane = threadIdx.x & 63;
  const int row = blockIdx.x * 4 + wave;

  float v = 0.f;
#pragma unroll
  for (int k = 0; k < SPLITK; ++k)
    v += zpart[((size_t)k * M_DIM + row) * R_DIM + lane];

  float a = fabsf(v);
  // rank-select the 16th-largest |z| (tie-safe): cnt_gt <= 15 < cnt_ge
  int cnt_gt = 0, cnt_ge = 0;
#pragma unroll
  for (int i = 0; i < 64; ++i) {
    float o = __shfl(a, i);
    cnt_gt += (o > a) ? 1 : 0;
    cnt_ge += (o >= a) ? 1 : 0;
  }
  float cand = (cnt_gt <= 15 && cnt_ge > 15) ? a : -1.f;
#pragma unroll
  for (int off = 32; off; off >>= 1) cand = fmaxf(cand, __shfl_xor(cand, off));
  float thr = cand;
  float mask = 1.f / (1.f + __expf(-(a - thr) * 10.0f));  // TEMP=0.1
  xext[(size_t)row * KX + DK + lane] = f2bf_rne(v * mask);  // SCALE == 1.0
}

// ---------------- main GEMM: out[m][n] = sum_k xext[m][k]*wext[n][k] + bias[n] ----------------
// 128x128 tile, BK=32, 4 waves in 2x2, 4x4 16x16x32 MFMA per wave (m97 structure)
__global__ __launch_bounds__(256) void gemm_kernel(
    const unsigned short* __restrict__ Ag,   // [M_DIM][KX] bf16
    const unsigned short* __restrict__ Bg,   // [N_DIM][KX] bf16
    const float* __restrict__ bias,
    float* __restrict__ out) {
  __shared__ unsigned short As[128][32];  // 8 KB
  __shared__ unsigned short Bs[128][32];  // 8 KB

  const int tid = threadIdx.x;
  const int wave = tid >> 6;
  const int lane = tid & 63;
  const int bn = blockIdx.x, bm = blockIdx.y;
  const int rowBase = bm * 128, colBase = bn * 128;
  const int wm = (wave & 1) * 64, wn = (wave >> 1) * 64;

  const int c0 = wave, c1 = wave + 4;
  const int srow = lane >> 2;
  const int sseg = (lane & 3) * 8;

  const unsigned short* aP0 = Ag + (size_t)(rowBase + c0 * 16 + srow) * KX + sseg;
  const unsigned short* aP1 = Ag + (size_t)(rowBase + c1 * 16 + srow) * KX + sseg;
  const unsigned short* bP0 = Bg + (size_t)(colBase + c0 * 16 + srow) * KX + sseg;
  const unsigned short* bP1 = Bg + (size_t)(colBase + c1 * 16 + srow) * KX + sseg;
  unsigned short* aL0 = &As[c0 * 16][0];
  unsigned short* aL1 = &As[c1 * 16][0];
  unsigned short* bL0 = &Bs[c0 * 16][0];
  unsigned short* bL1 = &Bs[c1 * 16][0];

  f32x4 acc[4][4] = {};
  const int fr = lane & 15;
  const int fk = (lane >> 4) * 8;

  for (int k0 = 0; k0 < KX; k0 += 32) {
    __syncthreads();
    load16_to_lds(aP0 + k0, aL0);
    load16_to_lds(aP1 + k0, aL1);
    load16_to_lds(bP0 + k0, bL0);
    load16_to_lds(bP1 + k0, bL1);
    __syncthreads();

    bf16x8 afrag[4], bfrag[4];
#pragma unroll
    for (int i = 0; i < 4; ++i)
      afrag[i] = *(const bf16x8*)&As[wm + i * 16 + fr][fk];
#pragma unroll
    for (int j = 0; j < 4; ++j)
      bfrag[j] = *(const bf16x8*)&Bs[wn + j * 16 + fr][fk];
#pragma unroll
    for (int i = 0; i < 4; ++i)
#pragma unroll
      for (int j = 0; j < 4; ++j)
        acc[i][j] = __builtin_amdgcn_mfma_f32_16x16x32_bf16(afrag[i], bfrag[j],
                                                            acc[i][j], 0, 0, 0);
  }

  // epilogue: C/D layout col=lane&15, row=(lane>>4)*4+reg
  const int quad = lane >> 4;
#pragma unroll
  for (int j = 0; j < 4; ++j) {
    int col = colBase + wn + j * 16 + fr;
    float bv = bias[col];
#pragma unroll
    for (int i = 0; i < 4; ++i) {
      int row0 = rowBase + wm + i * 16 + quad * 4;
#pragma unroll
      for (int r = 0; r < 4; ++r)
        out[(size_t)(row0 + r) * N_DIM + col] = acc[i][j][r] + bv;
    }
  }
}

extern "C" void kernel_launch(void* const* d_in, const int* in_sizes, int n_in,
                              void* d_out, int out_size, void* d_ws, size_t ws_size,
                              hipStream_t stream) {
  const float* x    = (const float*)d_in[0];  // (4,2048,4096)
  const float* A    = (const float*)d_in[1];  // (64,4096)
  const float* B    = (const float*)d_in[2];  // (4096,64)
  const float* W    = (const float*)d_in[3];  // (4096,4096)
  const float* bias = (const float*)d_in[4];  // (4096,)
  float* out = (float*)d_out;

  // workspace layout (all 16B-aligned):
  //   xext  [8192][4160] bf16  = 68.16 MB
  //   wext  [4096][4160] bf16  = 34.08 MB
  //   abf   [64][4096]   bf16  =  0.52 MB
  //   zpart [8][8192][64] fp32 = 16.78 MB
  unsigned short* xext = (unsigned short*)d_ws;
  unsigned short* wext = xext + (size_t)M_DIM * KX;
  unsigned short* abf  = wext + (size_t)N_DIM * KX;
  float*          zpart = (float*)(abf + (size_t)R_DIM * DK);

  // x -> x_ext[:, :4096]
  cvt_bf16_kernel<<<(M_DIM * DK / 8 + 255) / 256, 256, 0, stream>>>(
      x, xext, 12, 4095, KX, 0, (long long)M_DIM * DK);
  // W -> w_ext[:, :4096]
  cvt_bf16_kernel<<<(N_DIM * DK / 8 + 255) / 256, 256, 0, stream>>>(
      W, wext, 12, 4095, KX, 0, (long long)N_DIM * DK);
  // B -> w_ext[:, 4096:]
  cvt_bf16_kernel<<<(N_DIM * R_DIM / 8 + 255) / 256, 256, 0, stream>>>(
      B, wext, 6, 63, KX, 4096, (long long)N_DIM * R_DIM);
  // A -> abf
  cvt_bf16_kernel<<<(R_DIM * DK / 8 + 255) / 256, 256, 0, stream>>>(
      A, abf, 12, 4095, DK, 0, (long long)R_DIM * DK);

  // z partials via MFMA split-K GEMM
  dim3 zgrid(M_DIM / 128, SPLITK);  // 64 x 8
  zgemm_kernel<<<zgrid, 256, 0, stream>>>(xext, abf, zpart);
  // reduce + soft-topk mask -> x_ext[:, 4096:]
  mask_kernel<<<M_DIM / 4, 256, 0, stream>>>(zpart, xext);

  dim3 grid(N_DIM / 128, M_DIM / 128);  // 32 x 64
  gemm_kernel<<<grid, 256, 0, stream>>>(xext, wext, bias, out);
}